// Round 3
// baseline (40.716 us; speedup 1.0000x reference)
//
#include <hip/hip_runtime.h>

// SeMCA fully-fused single kernel.
// 50 blocks = (b,g); each block owns the 25 pixels congruent to (ph,pw) mod 5
// and the output pixels congruent to (ph+3,pw+3) mod 5 — disjoint partitions.
#define BVO 28224   // 64*441 per-batch offset

__global__ __launch_bounds__(512) void semca_kernel(
    const float* __restrict__ x,  const float* __restrict__ wk, const float* __restrict__ bk,
    const float* __restrict__ w1,
    const float* __restrict__ bn_gamma, const float* __restrict__ bn_beta,
    const float* __restrict__ bn_mean,  const float* __restrict__ bn_var,
    const float* __restrict__ w2, const float* __restrict__ b2,
    const float* __restrict__ wvw, const float* __restrict__ bv,
    float* __restrict__ out)
{
    int blk = blockIdx.x;            // 50 = b*25 + g
    int b = blk / 25, g = blk % 25;
    int ph = g / 5, pw = g % 5;
    int tid  = threadIdx.x;
    int lane = tid & 63;
    int wvid = tid >> 6;             // 8 waves

    // LDS layout (58.4 KB)
    __shared__ float L[14592];
    float* k1s  = L;                 // 1600  [p][c]  (live: A2 -> end)
    float* att1 = L + 1600;          // 1600  [o][e]  (live: C -> E)
    float* smM  = L + 3200;          // 64
    float* smR  = L + 3264;          // 64
    float* redm = L + 3328;          // 512
    float* redz = L + 3840;          // 512
    float* sv   = L + 3328;          // 512 (aliases redm in phase F)
    float* xs   = L + 4352;          // 1600  [p][c]  (live: A1 -> B)
    float* kq   = L + 5952;          // 3200  [m][e]  (live: B -> C)
    float* w1s  = L + 9152;          // 1250          (live: A1 -> C)
    float* ws2  = L + 5952;          // 3175 (aliases kq in phase D/E)
    float* b2s  = L + 9152;          // 127  (aliases w1s in phase D/E)
    float* wTt  = L + 10402;         // 4096  swizzled [e][cv^s]

    // ---- Phase A1: stage x columns at this block's 25 pixels + w1 ----
    for (int idx = tid; idx < 1600; idx += 512) {
        int p = idx >> 6, c = idx & 63;
        int row = 5*(p/5) + ph, col = 5*(p%5) + pw;
        float v0 = 0.f;
        if (row < 21 && col < 21) v0 = x[b*BVO + c*441 + row*21 + col];
        xs[idx] = v0;
    }
    for (int idx = tid; idx < 1250; idx += 512) w1s[idx] = w1[g*1250 + idx];
    __syncthreads();

    // ---- Phase A2: k1 at the 25 pixels (depthwise conv over channel axis) ----
    for (int p = wvid; p < 25; p += 8) {
        int row = 5*(p/5) + ph, col = 5*(p%5) + pw;
        float acc = 0.f;
        if (row < 21 && col < 21) {
            int d = row*21 + col;
            const float* wkp = wk + d*441 + 220 - lane;   // +cp: offsets in [157,283]
            acc = bk[d];
            #pragma unroll
            for (int cp = 0; cp < 64; ++cp)
                acc += xs[p*64 + cp] * wkp[cp];
        }
        k1s[p*64 + lane] = acc;
    }
    __syncthreads();

    // ---- Phase B: materialize kq[50][64] (pure LDS re-index of xs / k1s) ----
    for (int idx = tid; idx < 3200; idx += 512) {
        int m = idx >> 6, e = idx & 63;
        int B = (m < 25) ? m : m - 25;
        int u = (B << 6) + e;                  // u = 25*c + p
        int c = u / 25, p = u - 25*c;
        kq[idx] = (m < 25) ? xs[p*64 + c] : k1s[p*64 + c];
    }
    __syncthreads();

    // ---- Phase C: att1 = relu(BN(w1[g] @ kq)) ----
    {
        float kqcol[50];
        #pragma unroll
        for (int m = 0; m < 50; ++m) kqcol[m] = kq[m*64 + lane];
        #pragma unroll
        for (int k = 0; k < 4; ++k) {
            int o = wvid + 8*k;
            if (o < 25) {
                float acc = 0.f;
                #pragma unroll
                for (int m = 0; m < 50; ++m) acc += w1s[o*50 + m] * kqcol[m];
                float inv = bn_gamma[g*25+o] * rsqrtf(bn_var[g*25+o] + 1e-5f);
                acc = (acc - bn_mean[g*25+o]) * inv + bn_beta[g*25+o];
                att1[o*64 + lane] = fmaxf(acc, 0.f);
            }
        }
    }
    __syncthreads();

    // ---- Phase D: stage w2 rows [157,284) (for E) + online softmax stats over 441 rows ----
    for (int idx = tid; idx < 3175; idx += 512) ws2[idx] = w2[g*11025 + 157*25 + idx];
    if (tid < 127) b2s[tid] = b2[g*441 + 157 + tid];

    float a1r[25];
    #pragma unroll
    for (int i = 0; i < 25; ++i) a1r[i] = att1[i*64 + lane];

    const float* w2g = w2 + g*11025;
    const float* b2g = b2 + g*441;
    float mxA = -1e30f, zA = 0.f, mxB = -1e30f, zB = 0.f;
    // rows o2 = wvid + 8k, k in [0,55); two interleaved exp chains
    for (int k = 0; k < 54; k += 2) {
        int o2a = __builtin_amdgcn_readfirstlane(wvid + 8*k);
        int o2b = o2a + 8;
        const float* wpa = w2g + o2a*25;
        const float* wpb = w2g + o2b*25;
        float va = b2g[o2a], vb = b2g[o2b];
        #pragma unroll
        for (int i = 0; i < 25; ++i) { va += wpa[i]*a1r[i]; vb += wpb[i]*a1r[i]; }
        float na = fmaxf(mxA, va);
        zA = zA * __expf(mxA - na) + __expf(va - na); mxA = na;
        float nb = fmaxf(mxB, vb);
        zB = zB * __expf(mxB - nb) + __expf(vb - nb); mxB = nb;
    }
    {   // k = 54 -> chain A
        int o2a = __builtin_amdgcn_readfirstlane(wvid + 432);
        const float* wpa = w2g + o2a*25;
        float va = b2g[o2a];
        #pragma unroll
        for (int i = 0; i < 25; ++i) va += wpa[i]*a1r[i];
        float na = fmaxf(mxA, va);
        zA = zA * __expf(mxA - na) + __expf(va - na); mxA = na;
    }
    if (wvid == 0) {  // row 440 -> chain B
        const float* wpb = w2g + 440*25;
        float vb = b2g[440];
        #pragma unroll
        for (int i = 0; i < 25; ++i) vb += wpb[i]*a1r[i];
        float nb = fmaxf(mxB, vb);
        zB = zB * __expf(mxB - nb) + __expf(vb - nb); mxB = nb;
    }
    float mx = fmaxf(mxA, mxB);
    float zz = zA * __expf(mxA - mx) + zB * __expf(mxB - mx);

    redm[wvid*64 + lane] = mx;
    redz[wvid*64 + lane] = zz;
    __syncthreads();
    if (wvid == 0) {
        float M = -1e30f;
        #pragma unroll
        for (int w = 0; w < 8; ++w) M = fmaxf(M, redm[w*64 + lane]);
        float Z = 0.f;
        #pragma unroll
        for (int w = 0; w < 8; ++w) Z += redz[w*64 + lane] * __expf(redm[w*64 + lane] - M);
        smM[lane] = M;
        smR[lane] = 1.f / Z;
    }
    __syncthreads();

    // ---- Phase E: window weights wTt[e][cv^s] = softmax(att2)[cv+220-e][e] ----
    {
        float Me = smM[lane], Re = smR[lane];
        int s = (lane & 15) << 2;                  // float-index XOR swizzle (4-aligned)
        #pragma unroll
        for (int k = 0; k < 8; ++k) {
            int cv = wvid + 8*k;
            int r = cv + 63 - lane;                // o2 - 157, in [0,127)
            const float* wp = ws2 + r*25;
            float acc = b2s[r];
            #pragma unroll
            for (int i = 0; i < 25; ++i) acc += wp[i] * a1r[i];
            wTt[lane*64 + (cv ^ s)] = __expf(acc - Me) * Re;
        }
    }
    __syncthreads();

    // ---- Phase F: per-pixel depthwise 3x3 v + 64-wide dot + residual ----
    int y0 = (ph + 3) % 5, x0 = (pw + 3) % 5;
    int ny = (21 - y0 + 4) / 5, nx = (21 - x0 + 4) / 5;
    int npix = ny * nx;
    for (int k = 0; k < 4; ++k) {
        int p = wvid + 8*k;
        if (p >= npix) continue;                  // wave-uniform
        int yy = y0 + 5*(p / nx), xx = x0 + 5*(p % nx);
        float vt = 0.f;
        if (yy >= 2 && xx >= 2) {                 // wave-uniform
            int vy = yy - 2, vx = xx - 2;
            float vval = bv[lane];
            const float* xp = x + b*BVO + lane*441;
            #pragma unroll
            for (int ky = 0; ky < 3; ++ky) {
                int r2 = vy + ky - 1;
                if (r2 < 0 || r2 >= 21) continue;
                #pragma unroll
                for (int kx = 0; kx < 3; ++kx) {
                    int c2 = vx + kx - 1;
                    if (c2 < 0 || c2 >= 21) continue;
                    vval += xp[r2*21 + c2] * wvw[lane*9 + ky*3 + kx];
                }
            }
            sv[wvid*64 + lane] = vval;            // same-wave LDS exchange
            const float4* wrow = (const float4*)(wTt + lane*64);
            int s4 = lane & 15;
            #pragma unroll
            for (int q4 = 0; q4 < 16; ++q4) {
                float4 w4 = wrow[q4 ^ s4];
                int cv0 = q4 * 4;
                vt += sv[wvid*64 + cv0 + 0] * w4.x;
                vt += sv[wvid*64 + cv0 + 1] * w4.y;
                vt += sv[wvid*64 + cv0 + 2] * w4.z;
                vt += sv[wvid*64 + cv0 + 3] * w4.w;
            }
        }
        int pk = ((yy + 2 - ph) / 5) * 5 + ((xx + 2 - pw) / 5);
        float kt = k1s[pk*64 + lane];             // 0 if padded position
        out[b*BVO + lane*441 + yy*21 + xx] = kt + vt;
    }
}

extern "C" void kernel_launch(void* const* d_in, const int* in_sizes, int n_in,
                              void* d_out, int out_size, void* d_ws, size_t ws_size,
                              hipStream_t stream) {
    const float* x        = (const float*)d_in[0];
    const float* wk       = (const float*)d_in[1];
    const float* bk       = (const float*)d_in[2];
    const float* w1       = (const float*)d_in[3];
    const float* bn_gamma = (const float*)d_in[4];
    const float* bn_beta  = (const float*)d_in[5];
    const float* bn_mean  = (const float*)d_in[6];
    const float* bn_var   = (const float*)d_in[7];
    const float* w2       = (const float*)d_in[8];
    const float* b2       = (const float*)d_in[9];
    const float* wv       = (const float*)d_in[10];
    const float* bv       = (const float*)d_in[11];

    float* out = (float*)d_out;

    hipLaunchKernelGGL(semca_kernel, dim3(50), dim3(512), 0, stream,
                       x, wk, bk, w1, bn_gamma, bn_beta, bn_mean, bn_var,
                       w2, b2, wv, bv, out);
}

// Round 4
// 38.690 us; speedup vs baseline: 1.0523x; 1.0523x over previous
//
#include <hip/hip_runtime.h>

// SeMCA v5: 3-kernel pipeline, phase-D (441-row att2) spread across 400 blocks.
// Sizes: bs=2, C=64, IMG=21, D=441, P=25, PAD1=220.
#define BVO 28224   // 64*441 per-batch offset

// ws layout (floats):
//  k1g   [50][25][64]      80000   (k1 at the 25 pixels of each (b,g), [p][c])
//  att1g [50][25][64]      80000   ([o][e])
//  att2c [50][127][64]    406400   (att2 rows o2 in [157,284))
//  pm    [400][64]         25600   (per-chunk softmax max)
//  pz    [400][64]         25600   (per-chunk softmax sum)

// ---------------- Kernel A: stage x, k1 (channel-axis depthwise conv), att1 ------------
__global__ __launch_bounds__(256) void kA(
    const float* __restrict__ x, const float* __restrict__ wk, const float* __restrict__ bk,
    const float* __restrict__ w1,
    const float* __restrict__ bn_gamma, const float* __restrict__ bn_beta,
    const float* __restrict__ bn_mean,  const float* __restrict__ bn_var,
    float* __restrict__ k1g, float* __restrict__ att1g)
{
    int blk = blockIdx.x;            // 50 = b*25+g
    int b = blk / 25, g = blk % 25;
    int ph = g / 5, pw = g % 5;
    int tid = threadIdx.x, lane = tid & 63, wv = tid >> 6;

    __shared__ float xs[1600];       // xs[u], u = 25*c + p  (kq Q-half is xs[m*64+e])
    __shared__ float k1u[1600];      // k1u[u], u = 25*c + p

    // A1: gather x at this block's 25 pixels (0 for padded pixels)
    for (int u = tid; u < 1600; u += 256) {
        int c = u / 25, p = u - 25 * c;
        int row = 5*(p/5) + ph, col = 5*(p%5) + pw;
        xs[u] = (row < 21 && col < 21) ? x[b*BVO + c*441 + row*21 + col] : 0.f;
    }
    __syncthreads();

    // A2: k1[p][c] = bk[d] + sum_cp xs[cp at p] * wk[d*441 + 220 + cp - c]
    for (int k = 0; k < 7; ++k) {
        int p = wv + 4*k;
        if (p >= 25) break;                       // wave-uniform
        int row = 5*(p/5) + ph, col = 5*(p%5) + pw;
        float acc = 0.f;
        if (row < 21 && col < 21) {               // wave-uniform
            int d = row*21 + col;
            const float* wkp = wk + d*441 + 220 - lane;
            float a0 = 0.f, a1 = 0.f;
            #pragma unroll
            for (int cp = 0; cp < 64; cp += 2) {
                a0 += xs[25*cp + p]       * wkp[cp];
                a1 += xs[25*(cp+1) + p]   * wkp[cp+1];
            }
            acc = bk[d] + a0 + a1;
        }
        k1u[lane*25 + p] = acc;
        k1g[blk*1600 + p*64 + lane] = acc;
    }
    __syncthreads();

    // C: att1[o][e] = relu(BN(sum_m w1[g][o][m] * kq[m][e])), kq col in regs
    float kq[50];
    #pragma unroll
    for (int m = 0; m < 25; ++m) kq[m] = xs[m*64 + lane];
    #pragma unroll
    for (int m = 0; m < 25; ++m) kq[25+m] = k1u[m*64 + lane];

    const float* w1g = w1 + g*1250;
    for (int k = 0; k < 7; ++k) {
        int o = wv + 4*k;
        if (o >= 25) break;                       // wave-uniform
        const float* wp = w1g + o*50;             // uniform -> s_loads
        float a0 = 0.f, a1 = 0.f;
        #pragma unroll
        for (int m = 0; m < 50; m += 2) { a0 += wp[m]*kq[m]; a1 += wp[m+1]*kq[m+1]; }
        float acc = a0 + a1;
        float inv = bn_gamma[g*25+o] * rsqrtf(bn_var[g*25+o] + 1e-5f);
        acc = (acc - bn_mean[g*25+o]) * inv + bn_beta[g*25+o];
        att1g[blk*1600 + o*64 + lane] = fmaxf(acc, 0.f);
    }
}

// ---------------- Kernel B: att2 row chunks + per-chunk softmax stats ------------------
__global__ __launch_bounds__(256) void kB(
    const float* __restrict__ att1g, const float* __restrict__ w2,
    const float* __restrict__ b2,
    float* __restrict__ att2c, float* __restrict__ pm, float* __restrict__ pz)
{
    int blk = blockIdx.x;            // 400 = bg*8 + ch
    int ch = blk & 7, bg = blk >> 3;
    int g  = bg % 25;
    int tid = threadIdx.x, lane = tid & 63, wv = tid >> 6;

    float a1r[25];
    #pragma unroll
    for (int i = 0; i < 25; ++i) a1r[i] = att1g[bg*1600 + i*64 + lane];

    int base = __builtin_amdgcn_readfirstlane(56*ch + 14*wv);   // 14 contiguous rows/wave
    const float* w2g = w2 + g*11025 + base*25;                  // uniform -> s_loads
    const float* b2g = b2 + g*441 + base;

    float vals[14];
    #pragma unroll
    for (int j = 0; j < 14; ++j) {
        int r = base + j;
        if (r < 441) {
            const float* wp = w2g + j*25;
            float a0 = 0.f, a1 = 0.f;
            #pragma unroll
            for (int i = 0; i < 24; i += 2) { a0 += wp[i]*a1r[i]; a1 += wp[i+1]*a1r[i+1]; }
            vals[j] = b2g[j] + a0 + a1 + wp[24]*a1r[24];
            if (r >= 157 && r < 284)
                att2c[(bg*127 + (r-157))*64 + lane] = vals[j];
        } else {
            vals[j] = -1e30f;
        }
    }

    float mx = vals[0];
    #pragma unroll
    for (int j = 1; j < 14; ++j) mx = fmaxf(mx, vals[j]);

    __shared__ float red[4][64];
    red[wv][lane] = mx;
    __syncthreads();
    float M = fmaxf(fmaxf(red[0][lane], red[1][lane]), fmaxf(red[2][lane], red[3][lane]));
    float z = 0.f;
    #pragma unroll
    for (int j = 0; j < 14; ++j) z += __expf(vals[j] - M);
    __syncthreads();
    red[wv][lane] = z;
    __syncthreads();
    if (wv == 0) {
        float Z = red[0][lane] + red[1][lane] + red[2][lane] + red[3][lane];
        pm[blk*64 + lane] = M;
        pz[blk*64 + lane] = Z;
    }
}

// ---------------- Kernel C: combine stats + window weights + v-conv + output -----------
__global__ __launch_bounds__(256) void kC(
    const float* __restrict__ x, const float* __restrict__ wvw, const float* __restrict__ bv,
    const float* __restrict__ k1g, const float* __restrict__ att2c,
    const float* __restrict__ pm, const float* __restrict__ pz,
    float* __restrict__ out)
{
    int blk = blockIdx.x;            // 50 = b*25+g
    int b = blk / 25, g = blk % 25;
    int ph = g / 5, pw = g % 5;
    int tid = threadIdx.x, lane = tid & 63, wv = tid >> 6;

    __shared__ float a2s[8128];      // att2 rows [157,284) x 64
    __shared__ float wT[4096];       // wT[cv][e]
    __shared__ float smM[64], smR[64];

    for (int i = tid; i < 8128; i += 256) a2s[i] = att2c[blk*8128 + i];
    if (tid < 64) {
        float M = -1e30f;
        #pragma unroll
        for (int c = 0; c < 8; ++c) M = fmaxf(M, pm[(blk*8 + c)*64 + tid]);
        float Z = 0.f;
        #pragma unroll
        for (int c = 0; c < 8; ++c)
            Z += pz[(blk*8 + c)*64 + tid] * __expf(pm[(blk*8 + c)*64 + tid] - M);
        smM[tid] = M;
        smR[tid] = 1.f / Z;
    }
    __syncthreads();

    // E: wT[cv][e] = exp(att2[cv+220-e][e] - M_e) / Z_e  (diagonal read, stride -63 ≡ 1 mod 32)
    float Me = smM[lane], Re = smR[lane];
    #pragma unroll
    for (int k = 0; k < 16; ++k) {
        int cv = wv + 4*k;
        wT[cv*64 + lane] = __expf(a2s[(cv + 63 - lane)*64 + lane] - Me) * Re;
    }
    __syncthreads();

    // F: per pixel: depthwise 3x3 v-conv (lane = channel), dot via readlane, + residual
    int y0 = (ph + 3) % 5, x0 = (pw + 3) % 5;
    int ny = (21 - y0 + 4) / 5, nx = (21 - x0 + 4) / 5;
    int npix = ny * nx;
    for (int k = 0; k < 7; ++k) {
        int p = wv + 4*k;
        if (p >= npix) break;                      // wave-uniform
        int yy = y0 + 5*(p / nx), xx = x0 + 5*(p % nx);
        float vt = 0.f;
        if (yy >= 2 && xx >= 2) {                  // wave-uniform
            int vy = yy - 2, vx = xx - 2;
            float vval = bv[lane];
            const float* xp = x + b*BVO + lane*441;
            #pragma unroll
            for (int ky = 0; ky < 3; ++ky) {
                int r2 = vy + ky - 1;
                if (r2 < 0 || r2 >= 21) continue;
                #pragma unroll
                for (int kx = 0; kx < 3; ++kx) {
                    int c2 = vx + kx - 1;
                    if (c2 < 0 || c2 >= 21) continue;
                    vval += xp[r2*21 + c2] * wvw[lane*9 + ky*3 + kx];
                }
            }
            #pragma unroll
            for (int cv = 0; cv < 64; ++cv) {
                float s = __uint_as_float(__builtin_amdgcn_readlane(__float_as_uint(vval), cv));
                vt += s * wT[cv*64 + lane];
            }
        }
        int pk = ((yy + 2 - ph) / 5) * 5 + ((xx + 2 - pw) / 5);
        float kt = k1g[blk*1600 + pk*64 + lane];
        out[b*BVO + lane*441 + yy*21 + xx] = kt + vt;
    }
}

extern "C" void kernel_launch(void* const* d_in, const int* in_sizes, int n_in,
                              void* d_out, int out_size, void* d_ws, size_t ws_size,
                              hipStream_t stream) {
    const float* x        = (const float*)d_in[0];
    const float* wk       = (const float*)d_in[1];
    const float* bk       = (const float*)d_in[2];
    const float* w1       = (const float*)d_in[3];
    const float* bn_gamma = (const float*)d_in[4];
    const float* bn_beta  = (const float*)d_in[5];
    const float* bn_mean  = (const float*)d_in[6];
    const float* bn_var   = (const float*)d_in[7];
    const float* w2       = (const float*)d_in[8];
    const float* b2       = (const float*)d_in[9];
    const float* wv       = (const float*)d_in[10];
    const float* bv       = (const float*)d_in[11];

    float* out   = (float*)d_out;
    float* k1g   = (float*)d_ws;        // 80000
    float* att1g = k1g + 80000;         // 80000
    float* att2c = att1g + 80000;       // 406400
    float* pm    = att2c + 406400;      // 25600
    float* pz    = pm + 25600;          // 25600

    hipLaunchKernelGGL(kA, dim3(50), dim3(256), 0, stream,
                       x, wk, bk, w1, bn_gamma, bn_beta, bn_mean, bn_var, k1g, att1g);
    hipLaunchKernelGGL(kB, dim3(400), dim3(256), 0, stream,
                       att1g, w2, b2, att2c, pm, pz);
    hipLaunchKernelGGL(kC, dim3(50), dim3(256), 0, stream,
                       x, wv, bv, k1g, att2c, pm, pz, out);
}